// Round 1
// baseline (365.024 us; speedup 1.0000x reference)
//
#include <hip/hip_runtime.h>
#include <hip/hip_cooperative_groups.h>
#include <math.h>

namespace cg = cooperative_groups;

// Problem constants (from reference setup_inputs)
#define BATCH 32
#define NPTS  4096
#define DCH   254            // input channels; output row = DCH + 2 = 256
#define OUTC  256
#define PB    32             // blocks (chunks) per batch
#define NBLK  (BATCH * PB)   // 1024 blocks total
#define EPSV  1e-5f

#define BFLOATS (NPTS * DCH)         // 1,040,384 floats per batch
#define B4      (BFLOATS / 4)        // 260,096 float4 per batch (batch base is 16B-aligned)
#define C4      (B4 / PB)            // 8,128 float4 per block chunk (= 128 rows)
#define ROWS_PER_BLK (BATCH * NPTS / NBLK)   // 128

// ---------------------------------------------------------------------------
// Single fused cooperative kernel.
//   Phase 1: block (b,j) reduces its CONTIGUOUS chunk (rows j*128..j*128+127 of
//            batch b) -> partials[blk]. Contiguity (vs the old strided walk)
//            makes phase 3 re-read the same lines this block just pulled, so
//            the second pass over x is served by L2/L3 (x = 133 MB < 256 MB L3).
//   grid.sync()
//   Phase 2: every wave redundantly folds its batch's 32 partials (256 B, L2-hot)
//            -> mean/std/inv in registers. Kills the separate finalize kernel.
//   Phase 3: normalize the SAME 128 rows. One wave per 256-col output row:
//            lane l owns cols 4l..4l+3; lane 63 splices mean (col 254) and
//            std (col 255). Output stores are float4 (row stride 1024 B);
//            input rows (1016 B stride) use 4 coalesced dword loads.
// Workspace `partials` is written unconditionally by every block before the
// sync, so the 0xAA-poisoned workspace needs no zero-init.
// ---------------------------------------------------------------------------
__global__ __launch_bounds__(256, 4) void ipn_fused(const float* __restrict__ x,
                                                    const float* __restrict__ w,
                                                    const float* __restrict__ bias,
                                                    float2* __restrict__ partials,
                                                    float* __restrict__ out) {
    const int blk  = blockIdx.x;
    const int b    = blk / PB;          // batch
    const int j    = blk % PB;          // chunk within batch
    const int tid  = threadIdx.x;
    const int lane = tid & 63;
    const int wv   = tid >> 6;          // wave 0..3

    // ---- phase 1: partial sum / sumsq over this block's contiguous chunk ----
    const float4* xb = (const float4*)(x + (size_t)b * BFLOATS);
    float s = 0.f, ss = 0.f;
    const int i0 = j * C4;
    for (int i = i0 + tid; i < i0 + C4; i += 256) {
        float4 v = xb[i];
        s  += (v.x + v.y) + (v.z + v.w);
        ss += (v.x * v.x + v.y * v.y) + (v.z * v.z + v.w * v.w);
    }
    #pragma unroll
    for (int off = 32; off > 0; off >>= 1) {
        s  += __shfl_down(s, off);
        ss += __shfl_down(ss, off);
    }
    __shared__ float ls[4], lss[4];
    if (lane == 0) { ls[wv] = s; lss[wv] = ss; }
    __syncthreads();
    if (tid == 0) {
        partials[blk] = make_float2((ls[0] + ls[1]) + (ls[2] + ls[3]),
                                    (lss[0] + lss[1]) + (lss[2] + lss[3]));
    }

    cg::this_grid().sync();

    // ---- phase 2: fold this batch's 32 partials (all waves, in-register) ----
    float2 p = partials[b * PB + (lane & 31)];
    float S = p.x, SS = p.y;
    #pragma unroll
    for (int off = 16; off > 0; off >>= 1) {   // butterfly: every lane gets totals
        S  += __shfl_xor(S, off);
        SS += __shfl_xor(SS, off);
    }
    const float invM = 1.0f / (float)BFLOATS;
    const float mean = S * invM;
    const float var  = fmaxf(SS * invM - mean * mean, 0.f);   // biased variance
    const float stdv = sqrtf(var);
    const float inv  = 1.0f / (stdv + EPSV);

    // ---- phase 3: normalize the same 128 rows this block reduced ----
    const float4 w4 = ((const float4*)w)[lane];
    const float4 b4 = ((const float4*)bias)[lane];
    const int c0   = lane * 4;
    const int row0 = blk * ROWS_PER_BLK;

    for (int r = wv; r < ROWS_PER_BLK; r += 4) {
        const int row = row0 + r;
        const float* xr = x + (size_t)row * DCH + c0;
        float4 v;
        if (c0 < 252) {
            v.x = (xr[0] - mean) * inv;
            v.y = (xr[1] - mean) * inv;
            v.z = (xr[2] - mean) * inv;
            v.w = (xr[3] - mean) * inv;
        } else {                               // lane 63: cols 252,253,254,255
            v.x = (xr[0] - mean) * inv;
            v.y = (xr[1] - mean) * inv;
            v.z = mean;
            v.w = stdv;
        }
        float4 o;
        o.x = v.x * w4.x + b4.x;
        o.y = v.y * w4.y + b4.y;
        o.z = v.z * w4.z + b4.z;
        o.w = v.w * w4.w + b4.w;
        ((float4*)(out + (size_t)row * OUTC))[lane] = o;
    }
}

// ---------------------------------------------------------------------------
extern "C" void kernel_launch(void* const* d_in, const int* in_sizes, int n_in,
                              void* d_out, int out_size, void* d_ws, size_t ws_size,
                              hipStream_t stream) {
    const float* x   = (const float*)d_in[0];   // [32, 4096, 254] fp32
    const float* wgt = (const float*)d_in[1];   // [256] fp32
    const float* bia = (const float*)d_in[2];   // [256] fp32
    float* out       = (float*)d_out;           // [32, 4096, 256] fp32

    float2* partials = (float2*)d_ws;           // 1024 * 8 B = 8 KB

    void* args[] = {(void*)&x, (void*)&wgt, (void*)&bia,
                    (void*)&partials, (void*)&out};
    hipLaunchCooperativeKernel((const void*)ipn_fused, dim3(NBLK), dim3(256),
                               args, 0, stream);
}

// Round 3
// 256.757 us; speedup vs baseline: 1.4217x; 1.4217x over previous
//
#include <hip/hip_runtime.h>
#include <math.h>

// Problem constants (from reference setup_inputs)
#define BATCH 32
#define NPTS  4096
#define DCH   254            // input channels; output row = DCH + 2 = 256
#define OUTC  256
#define PB    64             // partial-reduce chunks per batch
#define NBLK1 (BATCH * PB)   // 2048 reduce blocks
#define EPSV  1e-5f

#define BFLOATS (NPTS * DCH)     // 1,040,384 floats per batch
#define B4      (BFLOATS / 4)    // 260,096 float4 per batch (batch base 16B-aligned)
#define C4      (B4 / PB)        // 4,064 float4 per chunk (= 64 rows)

#define NORM_BLOCKS 4096         // 32 rows/block, 128 blocks per batch
#define ROWS_PER_BLK2 (BATCH * NPTS / NORM_BLOCKS)   // 32

// native clang vector type: required by __builtin_nontemporal_store
typedef float floatx4 __attribute__((ext_vector_type(4)));

// ---------------------------------------------------------------------------
// Kernel 1: per-batch partial reduction, contiguous chunks.
// Grid = 2048 blocks x 256 threads (8 blocks/CU -> full occupancy).
// Pure linear float4 sweep of x -> HBM-BW-bound; x lands in L3 for kernel 2.
// Every partials slot is written unconditionally (0xAA-poisoned ws needs no init).
// ---------------------------------------------------------------------------
__global__ __launch_bounds__(256) void ipn_reduce(const float* __restrict__ x,
                                                  float2* __restrict__ partials) {
    const int blk = blockIdx.x;
    const int b   = blk / PB;
    const int j   = blk % PB;
    const float4* xb = (const float4*)(x + (size_t)b * BFLOATS);

    float s = 0.f, ss = 0.f;
    const int i0 = j * C4;
    for (int i = i0 + threadIdx.x; i < i0 + C4; i += 256) {   // C4=4064: 15-16 iters
        float4 v = xb[i];
        s  += (v.x + v.y) + (v.z + v.w);
        ss += (v.x * v.x + v.y * v.y) + (v.z * v.z + v.w * v.w);
    }
    #pragma unroll
    for (int off = 32; off > 0; off >>= 1) {
        s  += __shfl_down(s, off);
        ss += __shfl_down(ss, off);
    }
    __shared__ float ls[4], lss[4];
    const int wv = threadIdx.x >> 6;
    if ((threadIdx.x & 63) == 0) { ls[wv] = s; lss[wv] = ss; }
    __syncthreads();
    if (threadIdx.x == 0) {
        partials[blk] = make_float2((ls[0]  + ls[1])  + (ls[2]  + ls[3]),
                                    (lss[0] + lss[1]) + (lss[2] + lss[3]));
    }
}

// ---------------------------------------------------------------------------
// Kernel 2: finalize (folded in) + normalize + concat(mean,std) + scale/bias.
// Grid = 4096 blocks x 256 threads; block handles 32 rows of ONE batch
// (128 blocks per batch), one wave per 256-col output row, 8 rows per wave.
//
// - Each wave redundantly folds its batch's 64 partials via a 64-lane
//   butterfly (512 B, L2-hot) -> mean/std/inv in registers; no finalize kernel.
// - x loads: 2x dwordx2 per lane (row stride 1016 B and lane offset 16B are
//   both 8-aligned -> float2 always legal; halves load-instruction count vs
//   4x dword). Lane 63 loads only cols 252,253 (cols 254,255 are spliced
//   mean/std constants) -- also avoids the 8 B OOB read past x on the last row.
// - scale/bias fused into one FMA/elem: v*(inv*w) + (b - mean*inv*w).
// - out stored with __builtin_nontemporal_store (native ext_vector type):
//   out (134 MB) must not evict the L3-resident x (133 MB) mid-pass -- LRU
//   would victimize exactly the not-yet-re-read tail of x.
// ---------------------------------------------------------------------------
__global__ __launch_bounds__(256) void ipn_norm(const float* __restrict__ x,
                                                const float* __restrict__ w,
                                                const float* __restrict__ bias,
                                                const float2* __restrict__ partials,
                                                float* __restrict__ out) {
    const int lane = threadIdx.x & 63;
    const int wv   = threadIdx.x >> 6;
    const int b    = blockIdx.x >> 7;          // 128 blocks per batch

    // ---- fold this batch's 64 partials (each wave redundantly, in-register) ----
    float2 p = partials[b * PB + lane];
    float S = p.x, SS = p.y;
    #pragma unroll
    for (int off = 32; off > 0; off >>= 1) {   // butterfly: every lane gets totals
        S  += __shfl_xor(S, off);
        SS += __shfl_xor(SS, off);
    }
    const float invM = 1.0f / (float)BFLOATS;
    const float mean = S * invM;
    const float var  = fmaxf(SS * invM - mean * mean, 0.f);   // biased variance
    const float stdv = sqrtf(var);
    const float inv  = 1.0f / (stdv + EPSV);

    // ---- per-lane fused scale/offset ----
    const int c0 = lane * 4;
    const float4 w4 = ((const float4*)w)[lane];
    const float4 b4 = ((const float4*)bias)[lane];
    float4 s4, o4;
    s4.x = inv * w4.x;  o4.x = b4.x - mean * s4.x;
    s4.y = inv * w4.y;  o4.y = b4.y - mean * s4.y;
    s4.z = inv * w4.z;  o4.z = b4.z - mean * s4.z;
    s4.w = inv * w4.w;  o4.w = b4.w - mean * s4.w;
    // lane 63 splice constants (cols 254=mean, 255=std), batch-invariant
    const float oz63 = mean * w4.z + b4.z;
    const float ow63 = stdv * w4.w + b4.w;

    const int row0 = blockIdx.x * ROWS_PER_BLK2;

    for (int r = wv; r < ROWS_PER_BLK2; r += 4) {
        const int row = row0 + r;
        const float* xr = x + (size_t)row * DCH + c0;
        const float2 lo = *(const float2*)xr;            // cols c0, c0+1
        floatx4 o;
        o.x = lo.x * s4.x + o4.x;
        o.y = lo.y * s4.y + o4.y;
        if (c0 < 252) {
            const float2 hi = *(const float2*)(xr + 2);  // cols c0+2, c0+3
            o.z = hi.x * s4.z + o4.z;
            o.w = hi.y * s4.w + o4.w;
        } else {                                          // lane 63
            o.z = oz63;
            o.w = ow63;
        }
        __builtin_nontemporal_store(o, (floatx4*)(out + (size_t)row * OUTC) + lane);
    }
}

// ---------------------------------------------------------------------------
extern "C" void kernel_launch(void* const* d_in, const int* in_sizes, int n_in,
                              void* d_out, int out_size, void* d_ws, size_t ws_size,
                              hipStream_t stream) {
    const float* x   = (const float*)d_in[0];   // [32, 4096, 254] fp32
    const float* wgt = (const float*)d_in[1];   // [256] fp32
    const float* bia = (const float*)d_in[2];   // [256] fp32
    float* out       = (float*)d_out;           // [32, 4096, 256] fp32

    float2* partials = (float2*)d_ws;           // 2048 * 8 B = 16 KB

    ipn_reduce<<<NBLK1, 256, 0, stream>>>(x, partials);
    ipn_norm<<<NORM_BLOCKS, 256, 0, stream>>>(x, wgt, bia, partials, out);
}